// Round 1
// baseline (1488.501 us; speedup 1.0000x reference)
//
#include <hip/hip_runtime.h>
#include <float.h>
#include <math.h>

#define N_NODES 50000
#define N_EDGES 1600000
#define NB      64
#define HID     128
#define TOT     (N_EDGES + N_NODES)
#define PARTS   16

__device__ __forceinline__ float gelu_f(float x){
    return 0.5f * x * (1.0f + erff(x * 0.70710678118654752440f));
}

// block of 128 threads (2 waves) sum-reduce; red must be float[>=2] shared
__device__ __forceinline__ float blk_sum128(float v, float* red){
    #pragma unroll
    for (int m = 32; m > 0; m >>= 1) v += __shfl_xor(v, m, 64);
    __syncthreads();
    if ((threadIdx.x & 63) == 0) red[threadIdx.x >> 6] = v;
    __syncthreads();
    float r = red[0] + red[1];
    __syncthreads();
    return r;
}

// ---------------- encoder: h = gelu(LN(x@enc_w+enc_b)) ----------------
__global__ void enc_kernel(const float* __restrict__ x, const float* __restrict__ enc_w,
                           const float* __restrict__ enc_b, const float* __restrict__ enc_g,
                           const float* __restrict__ enc_beta, float* __restrict__ h)
{
    __shared__ float xs[12];
    __shared__ float red[2];
    int n = blockIdx.x, t = threadIdx.x;
    if (t < 12) xs[t] = x[n * 12 + t];
    __syncthreads();
    float acc = enc_b[t];
    #pragma unroll
    for (int k = 0; k < 12; k++) acc += xs[k] * enc_w[k * HID + t];
    float mean = blk_sum128(acc, red) * (1.0f / HID);
    float d = acc - mean;
    float var = blk_sum128(d * d, red) * (1.0f / HID);
    float y = d * rsqrtf(var + 1e-5f) * enc_g[t] + enc_beta[t];
    h[(size_t)n * HID + t] = gelu_f(y);
}

// ---------------- CSR build ----------------
__global__ void count_kernel(const int* __restrict__ ei, int* __restrict__ row_count){
    int i = blockIdx.x * 256 + threadIdx.x;
    if (i < N_EDGES) atomicAdd(&row_count[ei[N_EDGES + i]], 1);
}

__global__ void scan_kernel(const int* __restrict__ row_count, int* __restrict__ row_ptr){
    __shared__ int wsum[16];
    __shared__ int carry;
    int t = threadIdx.x;
    if (t == 0){ carry = 0; row_ptr[0] = 0; }
    __syncthreads();
    for (int base = 0; base < N_NODES; base += 1024){
        int i = base + t;
        int v = (i < N_NODES) ? (row_count[i] + 1) : 0;  // +1 self loop
        int lane = t & 63, w = t >> 6;
        int x = v;
        #pragma unroll
        for (int off = 1; off < 64; off <<= 1){
            int y = __shfl_up(x, off, 64);
            if (lane >= off) x += y;
        }
        if (lane == 63) wsum[w] = x;
        __syncthreads();
        if (t < 16){
            int s = wsum[t];
            #pragma unroll
            for (int off = 1; off < 16; off <<= 1){
                int y = __shfl_up(s, off, 64);
                if (t >= off) s += y;
            }
            wsum[t] = s;
        }
        __syncthreads();
        int woff = (w > 0) ? wsum[w - 1] : 0;
        int incl = x + woff + carry;
        if (i < N_NODES) row_ptr[i + 1] = incl;
        __syncthreads();
        if (t == 1023) carry = incl;
        __syncthreads();
    }
}

__global__ void scatter_kernel(const int* __restrict__ ei, int* __restrict__ cursor,
                               int* __restrict__ csr_src, int* __restrict__ csr_eid){
    int i = blockIdx.x * 256 + threadIdx.x;
    if (i >= TOT) return;
    int s, d;
    if (i < N_EDGES){ s = ei[i]; d = ei[N_EDGES + i]; }
    else { s = d = i - N_EDGES; }
    int pos = atomicAdd(&cursor[d], 1);
    csr_src[pos] = s;
    csr_eid[pos] = i;
}

// ---------------- self-loop attr: mean of incoming gelu(edge_attr@ee_w+b) ----------------
__global__ void loop_attr_kernel(const int* __restrict__ row_ptr, const int* __restrict__ csr_eid,
                                 const float* __restrict__ edge_attr, const float* __restrict__ ee_w,
                                 const float* __restrict__ ee_b, const int* __restrict__ row_count,
                                 float* __restrict__ loop_attr)
{
    __shared__ float w0[64], w1[64], w2[64], w3[64], bb[64];
    int n = blockIdx.x, c = threadIdx.x;
    w0[c] = ee_w[c]; w1[c] = ee_w[64 + c]; w2[c] = ee_w[128 + c]; w3[c] = ee_w[192 + c];
    bb[c] = ee_b[c];
    __syncthreads();
    int start = row_ptr[n], end = row_ptr[n + 1];
    float sum = 0.f;
    for (int p = start; p < end; ++p){
        int eid = csr_eid[p];
        if (eid < N_EDGES){
            float4 ea = ((const float4*)edge_attr)[eid];
            sum += gelu_f(ea.x * w0[c] + ea.y * w1[c] + ea.z * w2[c] + ea.w * w3[c] + bb[c]);
        }
    }
    int dg = row_count[n];
    loop_attr[(size_t)n * 64 + c] = sum / (float)max(dg, 1);
}

// ---------------- per-layer: W_e[k][h] = sum_c gat_edge_w[k][h*32+c]*att_edge[h][c] ----------------
__global__ void we_kernel(const float* __restrict__ gat_edge_w, const float* __restrict__ att_edge,
                          float* __restrict__ We)
{
    int t = threadIdx.x;          // 256 threads
    int k = t >> 2, hd = t & 3;
    float s = 0.f;
    #pragma unroll
    for (int c = 0; c < 32; c++) s += gat_edge_w[k * HID + hd * 32 + c] * att_edge[hd * 32 + c];
    We[k * 4 + hd] = s;
}

// ---------------- per-layer GEMM hh = h @ W, fused a_s/a_d ----------------
#define GROWS 8
__global__ void gemm_hh_kernel(const float* __restrict__ h, const float* __restrict__ W,
                               const float* __restrict__ att_s, const float* __restrict__ att_d,
                               float* __restrict__ hh, float* __restrict__ a_s, float* __restrict__ a_d)
{
    __shared__ float lh[GROWS * HID];
    int t = threadIdx.x;
    int n0 = blockIdx.x * GROWS;
    #pragma unroll
    for (int r = 0; r < GROWS; r++) lh[r * HID + t] = h[(size_t)(n0 + r) * HID + t];
    __syncthreads();
    float acc[GROWS];
    #pragma unroll
    for (int r = 0; r < GROWS; r++) acc[r] = 0.f;
    for (int k = 0; k < HID; k++){
        float w = W[k * HID + t];
        #pragma unroll
        for (int r = 0; r < GROWS; r++) acc[r] += lh[r * HID + k] * w;
    }
    float as_w = att_s[t], ad_w = att_d[t];
    int head = t >> 5;
    #pragma unroll
    for (int r = 0; r < GROWS; r++){
        hh[(size_t)(n0 + r) * HID + t] = acc[r];
        float vs = acc[r] * as_w, vd = acc[r] * ad_w;
        #pragma unroll
        for (int m = 16; m > 0; m >>= 1){
            vs += __shfl_xor(vs, m, 32);
            vd += __shfl_xor(vd, m, 32);
        }
        if ((t & 31) == 0){
            a_s[(n0 + r) * 4 + head] = vs;
            a_d[(n0 + r) * 4 + head] = vd;
        }
    }
}

// ---------------- per-layer: edge-attention term a_e per CSR position ----------------
__global__ void ae_kernel(const int* __restrict__ csr_eid, const float* __restrict__ edge_attr,
                          const float* __restrict__ loop_attr, const float* __restrict__ ee_w,
                          const float* __restrict__ ee_b, const float* __restrict__ We,
                          float* __restrict__ alpha)
{
    int p = blockIdx.x * 256 + threadIdx.x;
    if (p >= TOT) return;
    int eid = csr_eid[p];
    float ax = 0.f, ay = 0.f, az = 0.f, aw = 0.f;
    if (eid < N_EDGES){
        float4 ea = ((const float4*)edge_attr)[eid];
        #pragma unroll 8
        for (int k = 0; k < 64; k++){
            float v = gelu_f(ea.x * ee_w[k] + ea.y * ee_w[64 + k] + ea.z * ee_w[128 + k]
                             + ea.w * ee_w[192 + k] + ee_b[k]);
            float4 wv = ((const float4*)We)[k];
            ax += v * wv.x; ay += v * wv.y; az += v * wv.z; aw += v * wv.w;
        }
    } else {
        const float* la = loop_attr + (size_t)(eid - N_EDGES) * 64;
        #pragma unroll 8
        for (int k = 0; k < 64; k++){
            float v = la[k];
            float4 wv = ((const float4*)We)[k];
            ax += v * wv.x; ay += v * wv.y; az += v * wv.z; aw += v * wv.w;
        }
    }
    ((float4*)alpha)[p] = make_float4(ax, ay, az, aw);
}

// ---------------- per-layer: segment softmax + aggregation + residual + LN ----------------
__global__ void agg_kernel(const float* __restrict__ a_s, const float* __restrict__ a_d,
                           const int* __restrict__ row_ptr, const int* __restrict__ csr_src,
                           float* __restrict__ alpha, const float* __restrict__ hh,
                           float* __restrict__ h, const float* __restrict__ gat_bias,
                           const float* __restrict__ norm_g, const float* __restrict__ norm_b)
{
    __shared__ float red[8];
    int n = blockIdx.x, t = threadIdx.x;
    int start = row_ptr[n], end = row_ptr[n + 1];
    float4 ad = ((const float4*)a_d)[n];

    // pass 1: alpha = leaky(a_s[src] + a_d[n] + a_e), record max
    float4 mx = make_float4(-FLT_MAX, -FLT_MAX, -FLT_MAX, -FLT_MAX);
    for (int p = start + t; p < end; p += 128){
        int s = csr_src[p];
        float4 as = ((const float4*)a_s)[s];
        float4 ae = ((const float4*)alpha)[p];
        float4 al;
        al.x = as.x + ad.x + ae.x; al.x = al.x > 0.f ? al.x : 0.2f * al.x;
        al.y = as.y + ad.y + ae.y; al.y = al.y > 0.f ? al.y : 0.2f * al.y;
        al.z = as.z + ad.z + ae.z; al.z = al.z > 0.f ? al.z : 0.2f * al.z;
        al.w = as.w + ad.w + ae.w; al.w = al.w > 0.f ? al.w : 0.2f * al.w;
        ((float4*)alpha)[p] = al;
        mx.x = fmaxf(mx.x, al.x); mx.y = fmaxf(mx.y, al.y);
        mx.z = fmaxf(mx.z, al.z); mx.w = fmaxf(mx.w, al.w);
    }
    #pragma unroll
    for (int m = 32; m > 0; m >>= 1){
        mx.x = fmaxf(mx.x, __shfl_xor(mx.x, m, 64));
        mx.y = fmaxf(mx.y, __shfl_xor(mx.y, m, 64));
        mx.z = fmaxf(mx.z, __shfl_xor(mx.z, m, 64));
        mx.w = fmaxf(mx.w, __shfl_xor(mx.w, m, 64));
    }
    __syncthreads();
    if ((t & 63) == 0){ int w = t >> 6; red[w*4+0]=mx.x; red[w*4+1]=mx.y; red[w*4+2]=mx.z; red[w*4+3]=mx.w; }
    __syncthreads();
    float4 M;
    M.x = fmaxf(red[0], red[4]); M.y = fmaxf(red[1], red[5]);
    M.z = fmaxf(red[2], red[6]); M.w = fmaxf(red[3], red[7]);
    __syncthreads();

    // pass 2: exp and sum
    float4 sm = make_float4(0.f, 0.f, 0.f, 0.f);
    for (int p = start + t; p < end; p += 128){
        float4 al = ((const float4*)alpha)[p];
        float4 e;
        e.x = expf(al.x - M.x); e.y = expf(al.y - M.y);
        e.z = expf(al.z - M.z); e.w = expf(al.w - M.w);
        ((float4*)alpha)[p] = e;
        sm.x += e.x; sm.y += e.y; sm.z += e.z; sm.w += e.w;
    }
    #pragma unroll
    for (int m = 32; m > 0; m >>= 1){
        sm.x += __shfl_xor(sm.x, m, 64); sm.y += __shfl_xor(sm.y, m, 64);
        sm.z += __shfl_xor(sm.z, m, 64); sm.w += __shfl_xor(sm.w, m, 64);
    }
    __syncthreads();
    if ((t & 63) == 0){ int w = t >> 6; red[w*4+0]=sm.x; red[w*4+1]=sm.y; red[w*4+2]=sm.z; red[w*4+3]=sm.w; }
    __syncthreads();
    float4 D;
    D.x = red[0] + red[4]; D.y = red[1] + red[5];
    D.z = red[2] + red[6]; D.w = red[3] + red[7];
    __syncthreads();

    // pass 3: agg = (sum_e ex_e * hh[src_e]) / (denom + eps)
    int head = t >> 5;
    float Dh = (head == 0) ? D.x : (head == 1) ? D.y : (head == 2) ? D.z : D.w;
    float invd = 1.0f / (Dh + 1e-16f);
    float acc = 0.f;
    for (int p = start; p < end; ++p){
        int s = csr_src[p];
        float wv = alpha[(size_t)p * 4 + head];
        acc += wv * hh[(size_t)s * HID + t];
    }
    float y = h[(size_t)n * HID + t] + acc * invd + gat_bias[t];

    // residual + LayerNorm (in place)
    float mean = blk_sum128(y, red) * (1.0f / HID);
    float d2 = y - mean;
    float var = blk_sum128(d2 * d2, red) * (1.0f / HID);
    h[(size_t)n * HID + t] = d2 * rsqrtf(var + 1e-5f) * norm_g[t] + norm_b[t];
}

// ---------------- pooling ----------------
__global__ void bounds_kernel(const int* __restrict__ batch, int* __restrict__ bstart){
    int b = threadIdx.x;
    if (b > NB) return;
    int lo = 0, hi = N_NODES;
    while (lo < hi){
        int mid = (lo + hi) >> 1;
        if (batch[mid] < b) lo = mid + 1; else hi = mid;
    }
    bstart[b] = lo;
}

__global__ void pool_kernel(const float* __restrict__ h, const int* __restrict__ bstart,
                            float* __restrict__ psum, float* __restrict__ pmax){
    int b = blockIdx.x, part = blockIdx.y, t = threadIdx.x;
    int s = bstart[b], e = bstart[b + 1];
    int len = e - s;
    int chunk = (len + PARTS - 1) / PARTS;
    int cs = s + part * chunk;
    int ce = min(cs + chunk, e);
    float sum = 0.f, mx = -FLT_MAX;
    for (int n = cs; n < ce; ++n){
        float v = h[(size_t)n * HID + t];
        sum += v; mx = fmaxf(mx, v);
    }
    int slot = (b * PARTS + part) * HID + t;
    psum[slot] = sum;
    pmax[slot] = mx;
}

// ---------------- readout MLP + sigmoid ----------------
__global__ void mlp_kernel(const float* __restrict__ psum, const float* __restrict__ pmax,
                           const int* __restrict__ bstart,
                           const float* __restrict__ fw1, const float* __restrict__ fb1,
                           const float* __restrict__ fw2, const float* __restrict__ fb2,
                           const float* __restrict__ cw1, const float* __restrict__ cb1,
                           const float* __restrict__ cw2, const float* __restrict__ cb2,
                           float* __restrict__ out)
{
    __shared__ float g[256];
    __shared__ float y1[128];
    __shared__ float y2[64];
    __shared__ float y3[64];
    __shared__ float red[2];
    int b = blockIdx.x, t = threadIdx.x;
    float sum = 0.f, mx = -FLT_MAX;
    for (int p = 0; p < PARTS; p++){
        int slot = (b * PARTS + p) * HID + t;
        sum += psum[slot];
        mx = fmaxf(mx, pmax[slot]);
    }
    int cnt = bstart[b + 1] - bstart[b];
    float mean = sum / (float)max(cnt, 1);
    if (cnt <= 0) mx = 0.f;
    g[t] = mean; g[128 + t] = mx;
    __syncthreads();
    float a1 = fb1[t];
    for (int k = 0; k < 256; k++) a1 += g[k] * fw1[k * 128 + t];
    y1[t] = gelu_f(a1);
    __syncthreads();
    if (t < 64){
        float a2 = fb2[t];
        for (int k = 0; k < 128; k++) a2 += y1[k] * fw2[k * 64 + t];
        y2[t] = gelu_f(a2);
    }
    __syncthreads();
    if (t < 64){
        float a3 = cb1[t];
        for (int k = 0; k < 64; k++) a3 += y2[k] * cw1[k * 64 + t];
        y3[t] = gelu_f(a3);
    }
    __syncthreads();
    float v = (t < 64) ? y3[t] * cw2[t] : 0.f;
    float s = blk_sum128(v, red);
    if (t == 0){
        float logit = s + cb2[0];
        out[b] = 1.0f / (1.0f + expf(-logit));
    }
}

extern "C" void kernel_launch(void* const* d_in, const int* in_sizes, int n_in,
                              void* d_out, int out_size, void* d_ws, size_t ws_size,
                              hipStream_t stream)
{
    const float* x         = (const float*)d_in[0];
    const float* edge_attr = (const float*)d_in[1];
    const int*   edge_idx  = (const int*)  d_in[2];
    const int*   batch     = (const int*)  d_in[3];
    const float* enc_w     = (const float*)d_in[4];
    const float* enc_b     = (const float*)d_in[5];
    const float* enc_g     = (const float*)d_in[6];
    const float* enc_beta  = (const float*)d_in[7];
    const float* ee_w      = (const float*)d_in[8];
    const float* ee_b      = (const float*)d_in[9];
    const float* gat_lin_w = (const float*)d_in[10];
    const float* gat_edge_w= (const float*)d_in[11];
    const float* att_src   = (const float*)d_in[12];
    const float* att_dst   = (const float*)d_in[13];
    const float* att_edge  = (const float*)d_in[14];
    const float* gat_bias  = (const float*)d_in[15];
    const float* norm_g    = (const float*)d_in[16];
    const float* norm_b    = (const float*)d_in[17];
    const float* fw1       = (const float*)d_in[18];
    const float* fb1       = (const float*)d_in[19];
    const float* fw2       = (const float*)d_in[20];
    const float* fb2       = (const float*)d_in[21];
    const float* cw1       = (const float*)d_in[22];
    const float* cb1       = (const float*)d_in[23];
    const float* cw2       = (const float*)d_in[24];
    const float* cb2       = (const float*)d_in[25];
    float* out = (float*)d_out;

    char* wsp = (char*)d_ws;
    size_t off = 0;
    auto alloc = [&](size_t bytes) -> void* {
        void* p = wsp + off;
        off += (bytes + 255) & ~(size_t)255;
        return p;
    };
    float* h        = (float*)alloc((size_t)N_NODES * HID * 4);
    float* hh       = (float*)alloc((size_t)N_NODES * HID * 4);
    float* loop_attr= (float*)alloc((size_t)N_NODES * 64 * 4);
    float* a_s      = (float*)alloc((size_t)N_NODES * 4 * 4);
    float* a_d      = (float*)alloc((size_t)N_NODES * 4 * 4);
    float* alpha    = (float*)alloc((size_t)TOT * 4 * 4);
    int*   csr_src  = (int*)  alloc((size_t)TOT * 4);
    int*   csr_eid  = (int*)  alloc((size_t)TOT * 4);
    int*   row_ptr  = (int*)  alloc((size_t)(N_NODES + 1) * 4);
    int*   cursor   = (int*)  alloc((size_t)N_NODES * 4);
    int*   row_count= (int*)  alloc((size_t)N_NODES * 4);
    float* We       = (float*)alloc(64 * 4 * 4);
    int*   bstart   = (int*)  alloc((NB + 1) * 4);
    float* psum     = (float*)alloc((size_t)NB * PARTS * HID * 4);
    float* pmax     = (float*)alloc((size_t)NB * PARTS * HID * 4);

    // encoder
    hipLaunchKernelGGL(enc_kernel, dim3(N_NODES), dim3(128), 0, stream,
                       x, enc_w, enc_b, enc_g, enc_beta, h);

    // CSR build
    hipMemsetAsync(row_count, 0, (size_t)N_NODES * 4, stream);
    hipLaunchKernelGGL(count_kernel, dim3((N_EDGES + 255) / 256), dim3(256), 0, stream,
                       edge_idx, row_count);
    hipLaunchKernelGGL(scan_kernel, dim3(1), dim3(1024), 0, stream, row_count, row_ptr);
    hipMemcpyAsync(cursor, row_ptr, (size_t)N_NODES * 4, hipMemcpyDeviceToDevice, stream);
    hipLaunchKernelGGL(scatter_kernel, dim3((TOT + 255) / 256), dim3(256), 0, stream,
                       edge_idx, cursor, csr_src, csr_eid);

    // self-loop attributes
    hipLaunchKernelGGL(loop_attr_kernel, dim3(N_NODES), dim3(64), 0, stream,
                       row_ptr, csr_eid, edge_attr, ee_w, ee_b, row_count, loop_attr);

    // GAT layers
    for (int l = 0; l < 3; l++){
        hipLaunchKernelGGL(we_kernel, dim3(1), dim3(256), 0, stream,
                           gat_edge_w + (size_t)l * 64 * HID, att_edge + (size_t)l * HID, We);
        hipLaunchKernelGGL(gemm_hh_kernel, dim3(N_NODES / GROWS), dim3(128), 0, stream,
                           h, gat_lin_w + (size_t)l * HID * HID,
                           att_src + (size_t)l * HID, att_dst + (size_t)l * HID,
                           hh, a_s, a_d);
        hipLaunchKernelGGL(ae_kernel, dim3((TOT + 255) / 256), dim3(256), 0, stream,
                           csr_eid, edge_attr, loop_attr, ee_w, ee_b, We, alpha);
        hipLaunchKernelGGL(agg_kernel, dim3(N_NODES), dim3(128), 0, stream,
                           a_s, a_d, row_ptr, csr_src, alpha, hh, h,
                           gat_bias + (size_t)l * HID, norm_g + (size_t)l * HID,
                           norm_b + (size_t)l * HID);
    }

    // pooling + MLP
    hipLaunchKernelGGL(bounds_kernel, dim3(1), dim3(128), 0, stream, batch, bstart);
    hipLaunchKernelGGL(pool_kernel, dim3(NB, PARTS), dim3(128), 0, stream, h, bstart, psum, pmax);
    hipLaunchKernelGGL(mlp_kernel, dim3(NB), dim3(128), 0, stream,
                       psum, pmax, bstart, fw1, fb1, fw2, fb2, cw1, cb1, cw2, cb2, out);
}

// Round 2
// 1255.529 us; speedup vs baseline: 1.1856x; 1.1856x over previous
//
#include <hip/hip_runtime.h>
#include <float.h>
#include <math.h>

#define N_NODES 50000
#define N_EDGES 1600000
#define NB      64
#define HID     128
#define TOT     (N_EDGES + N_NODES)
#define PARTS   16
#define CAP     256   // max degree cached in LDS (data max ~70); spill path handles more

__device__ __forceinline__ float gelu_f(float x){
    return 0.5f * x * (1.0f + erff(x * 0.70710678118654752440f));
}

__device__ __forceinline__ float bf2f(unsigned short u){
    union { unsigned int i; float f; } c; c.i = ((unsigned int)u) << 16; return c.f;
}
__device__ __forceinline__ unsigned short f2bf(float x){
    union { float f; unsigned int i; } c; c.f = x;
    unsigned int r = c.i + 0x7fffu + ((c.i >> 16) & 1u);
    return (unsigned short)(r >> 16);
}
__device__ __forceinline__ uint2 pack4(float a, float b, float cc, float d){
    uint2 r;
    r.x = (unsigned int)f2bf(a) | ((unsigned int)f2bf(b) << 16);
    r.y = (unsigned int)f2bf(cc) | ((unsigned int)f2bf(d) << 16);
    return r;
}
__device__ __forceinline__ float4 unpack4(uint2 v){
    return make_float4(bf2f(v.x & 0xffff), bf2f(v.x >> 16),
                       bf2f(v.y & 0xffff), bf2f(v.y >> 16));
}

// block of 128 threads (2 waves) sum-reduce; red must be float[>=2] shared
__device__ __forceinline__ float blk_sum128(float v, float* red){
    #pragma unroll
    for (int m = 32; m > 0; m >>= 1) v += __shfl_xor(v, m, 64);
    __syncthreads();
    if ((threadIdx.x & 63) == 0) red[threadIdx.x >> 6] = v;
    __syncthreads();
    float r = red[0] + red[1];
    __syncthreads();
    return r;
}

// ---------------- encoder: h = gelu(LN(x@enc_w+enc_b)) ----------------
__global__ void enc_kernel(const float* __restrict__ x, const float* __restrict__ enc_w,
                           const float* __restrict__ enc_b, const float* __restrict__ enc_g,
                           const float* __restrict__ enc_beta, float* __restrict__ h)
{
    __shared__ float xs[12];
    __shared__ float red[2];
    int n = blockIdx.x, t = threadIdx.x;
    if (t < 12) xs[t] = x[n * 12 + t];
    __syncthreads();
    float acc = enc_b[t];
    #pragma unroll
    for (int k = 0; k < 12; k++) acc += xs[k] * enc_w[k * HID + t];
    float mean = blk_sum128(acc, red) * (1.0f / HID);
    float d = acc - mean;
    float var = blk_sum128(d * d, red) * (1.0f / HID);
    float y = d * rsqrtf(var + 1e-5f) * enc_g[t] + enc_beta[t];
    h[(size_t)n * HID + t] = gelu_f(y);
}

// ---------------- CSR build ----------------
__global__ void count_kernel(const int* __restrict__ ei, int* __restrict__ row_count){
    int i = blockIdx.x * 256 + threadIdx.x;
    if (i < N_EDGES) atomicAdd(&row_count[ei[N_EDGES + i]], 1);
}

__global__ void scan_kernel(const int* __restrict__ row_count, int* __restrict__ row_ptr){
    __shared__ int wsum[16];
    __shared__ int carry;
    int t = threadIdx.x;
    if (t == 0){ carry = 0; row_ptr[0] = 0; }
    __syncthreads();
    for (int base = 0; base < N_NODES; base += 1024){
        int i = base + t;
        int v = (i < N_NODES) ? (row_count[i] + 1) : 0;  // +1 self loop
        int lane = t & 63, w = t >> 6;
        int x = v;
        #pragma unroll
        for (int off = 1; off < 64; off <<= 1){
            int y = __shfl_up(x, off, 64);
            if (lane >= off) x += y;
        }
        if (lane == 63) wsum[w] = x;
        __syncthreads();
        if (t < 16){
            int s = wsum[t];
            #pragma unroll
            for (int off = 1; off < 16; off <<= 1){
                int y = __shfl_up(s, off, 64);
                if (t >= off) s += y;
            }
            wsum[t] = s;
        }
        __syncthreads();
        int woff = (w > 0) ? wsum[w - 1] : 0;
        int incl = x + woff + carry;
        if (i < N_NODES) row_ptr[i + 1] = incl;
        __syncthreads();
        if (t == 1023) carry = incl;
        __syncthreads();
    }
}

__global__ void scatter_kernel(const int* __restrict__ ei, int* __restrict__ cursor,
                               int* __restrict__ csr_src, int* __restrict__ epos,
                               int* __restrict__ self_pos){
    int i = blockIdx.x * 256 + threadIdx.x;
    if (i >= TOT) return;
    int s, d;
    if (i < N_EDGES){ s = ei[i]; d = ei[N_EDGES + i]; }
    else { s = d = i - N_EDGES; }
    int pos = atomicAdd(&cursor[d], 1);
    csr_src[pos] = s;
    if (i < N_EDGES) epos[i] = pos; else self_pos[d] = pos;
}

// ---------------- We3[l][k][h] = sum_c gat_edge_w[l][k][h*32+c]*att_edge[l][h*32+c] ----------------
__global__ void we3_kernel(const float* __restrict__ gat_edge_w, const float* __restrict__ att_edge,
                           float* __restrict__ We3)
{
    int t = threadIdx.x;          // 256 threads
    int k = t >> 2, hd = t & 3;
    for (int l = 0; l < 3; l++){
        float s = 0.f;
        #pragma unroll
        for (int c = 0; c < 32; c++)
            s += gat_edge_w[(size_t)l * 64 * HID + k * HID + hd * 32 + c]
               * att_edge[l * HID + hd * 32 + c];
        We3[(l * 64 + k) * 4 + hd] = s;
    }
}

// ---------------- per-edge a_e for ALL 3 layers, scattered to CSR position order ----------------
__global__ void ae_all_kernel(const float4* __restrict__ edge_attr, const float* __restrict__ ee_w,
                              const float* __restrict__ ee_b, const float* __restrict__ We3,
                              const int* __restrict__ epos,
                              uint2* __restrict__ al0, uint2* __restrict__ al1, uint2* __restrict__ al2)
{
    int e = blockIdx.x * 256 + threadIdx.x;
    if (e >= N_EDGES) return;
    float4 ea = edge_attr[e];
    float acc[12];
    #pragma unroll
    for (int i = 0; i < 12; i++) acc[i] = 0.f;
    #pragma unroll 4
    for (int k = 0; k < 64; k++){
        float v = gelu_f(ea.x * ee_w[k] + ea.y * ee_w[64 + k] + ea.z * ee_w[128 + k]
                         + ea.w * ee_w[192 + k] + ee_b[k]);
        #pragma unroll
        for (int l = 0; l < 3; l++){
            float4 wv = ((const float4*)We3)[l * 64 + k];
            acc[l*4+0] += v * wv.x; acc[l*4+1] += v * wv.y;
            acc[l*4+2] += v * wv.z; acc[l*4+3] += v * wv.w;
        }
    }
    int p = epos[e];
    al0[p] = pack4(acc[0], acc[1], acc[2],  acc[3]);
    al1[p] = pack4(acc[4], acc[5], acc[6],  acc[7]);
    al2[p] = pack4(acc[8], acc[9], acc[10], acc[11]);
}

// ---------------- self-loop a_e = mean over incoming real edges (linearity of the dot) ----------------
__global__ void selfae_kernel(const int* __restrict__ row_ptr, const int* __restrict__ self_pos,
                              uint2* __restrict__ al0, uint2* __restrict__ al1, uint2* __restrict__ al2)
{
    __shared__ float s[48];
    int n = blockIdx.x, t = threadIdx.x;   // 64 threads
    int start = row_ptr[n], end = row_ptr[n + 1], sp = self_pos[n];
    int deg = end - start - 1;
    if (t < 48){
        int g = t / 12, c = t % 12, l = c >> 2, hd = c & 3;
        const unsigned short* buf = (const unsigned short*)(l == 0 ? al0 : l == 1 ? al1 : al2);
        float sum = 0.f;
        for (int p = start + g; p < end; p += 4){
            if (p == sp) continue;
            sum += bf2f(buf[(size_t)p * 4 + hd]);
        }
        s[t] = sum;
    }
    __syncthreads();
    if (t < 12){
        int l = t >> 2, hd = t & 3;
        float m = (s[t] + s[t + 12] + s[t + 24] + s[t + 36]) / (float)max(deg, 1);
        unsigned short* buf = (unsigned short*)(l == 0 ? al0 : l == 1 ? al1 : al2);
        buf[(size_t)sp * 4 + hd] = f2bf(m);
    }
}

// ---------------- per-layer GEMM hh = h @ W (bf16 out), fused a_s/a_d ----------------
#define GROWS 8
__global__ void gemm_hh_kernel(const float* __restrict__ h, const float* __restrict__ W,
                               const float* __restrict__ att_s, const float* __restrict__ att_d,
                               unsigned short* __restrict__ hh, float* __restrict__ a_s,
                               float* __restrict__ a_d)
{
    __shared__ float lh[GROWS * HID];
    int t = threadIdx.x;
    int n0 = blockIdx.x * GROWS;
    #pragma unroll
    for (int r = 0; r < GROWS; r++) lh[r * HID + t] = h[(size_t)(n0 + r) * HID + t];
    __syncthreads();
    float acc[GROWS];
    #pragma unroll
    for (int r = 0; r < GROWS; r++) acc[r] = 0.f;
    for (int k = 0; k < HID; k++){
        float w = W[k * HID + t];
        #pragma unroll
        for (int r = 0; r < GROWS; r++) acc[r] += lh[r * HID + k] * w;
    }
    float as_w = att_s[t], ad_w = att_d[t];
    int head = t >> 5;
    #pragma unroll
    for (int r = 0; r < GROWS; r++){
        hh[(size_t)(n0 + r) * HID + t] = f2bf(acc[r]);
        float vs = acc[r] * as_w, vd = acc[r] * ad_w;
        #pragma unroll
        for (int m = 16; m > 0; m >>= 1){
            vs += __shfl_xor(vs, m, 32);
            vd += __shfl_xor(vd, m, 32);
        }
        if ((t & 31) == 0){
            a_s[(n0 + r) * 4 + head] = vs;
            a_d[(n0 + r) * 4 + head] = vd;
        }
    }
}

// ---------------- fused: leaky+exp+segsum+aggregate+residual+LN (no max-sub needed) ----------------
__global__ void agg_kernel(const float4* __restrict__ a_s, const float4* __restrict__ a_d,
                           const int* __restrict__ row_ptr, const int* __restrict__ csr_src,
                           uint2* __restrict__ alpha, const unsigned short* __restrict__ hh,
                           float* __restrict__ h, const float* __restrict__ gat_bias,
                           const float* __restrict__ norm_g, const float* __restrict__ norm_b)
{
    __shared__ float exs[CAP * 4];
    __shared__ int   isrc[CAP];
    __shared__ float red[8];
    int n = blockIdx.x, t = threadIdx.x;
    int start = row_ptr[n], end = row_ptr[n + 1];
    float4 ad = a_d[n];

    // phase A: alpha = leaky(a_s[src]+a_d[n]+a_e); ex = exp(alpha); sum
    float4 sm = make_float4(0.f, 0.f, 0.f, 0.f);
    for (int p = start + t; p < end; p += 128){
        int idx = p - start;
        int s = csr_src[p];
        float4 as = a_s[s];
        float4 ae = unpack4(alpha[p]);
        float4 al;
        al.x = as.x + ad.x + ae.x; al.x = al.x > 0.f ? al.x : 0.2f * al.x;
        al.y = as.y + ad.y + ae.y; al.y = al.y > 0.f ? al.y : 0.2f * al.y;
        al.z = as.z + ad.z + ae.z; al.z = al.z > 0.f ? al.z : 0.2f * al.z;
        al.w = as.w + ad.w + ae.w; al.w = al.w > 0.f ? al.w : 0.2f * al.w;
        float4 e;
        e.x = __expf(al.x); e.y = __expf(al.y); e.z = __expf(al.z); e.w = __expf(al.w);
        sm.x += e.x; sm.y += e.y; sm.z += e.z; sm.w += e.w;
        if (idx < CAP){
            exs[idx*4+0] = e.x; exs[idx*4+1] = e.y; exs[idx*4+2] = e.z; exs[idx*4+3] = e.w;
            isrc[idx] = s;
        } else {
            alpha[p] = pack4(e.x, e.y, e.z, e.w);   // spill (rare)
        }
    }
    #pragma unroll
    for (int m = 32; m > 0; m >>= 1){
        sm.x += __shfl_xor(sm.x, m, 64); sm.y += __shfl_xor(sm.y, m, 64);
        sm.z += __shfl_xor(sm.z, m, 64); sm.w += __shfl_xor(sm.w, m, 64);
    }
    __syncthreads();
    if ((t & 63) == 0){ int w = t >> 6; red[w*4+0]=sm.x; red[w*4+1]=sm.y; red[w*4+2]=sm.z; red[w*4+3]=sm.w; }
    __syncthreads();
    float4 D;
    D.x = red[0] + red[4]; D.y = red[1] + red[5];
    D.z = red[2] + red[6]; D.w = red[3] + red[7];
    __syncthreads();

    // phase B: acc = sum_p ex_p * hh[src_p]; y = h + acc/denom + bias; LN
    int head = t >> 5;
    float Dh = (head == 0) ? D.x : (head == 1) ? D.y : (head == 2) ? D.z : D.w;
    float invd = 1.0f / (Dh + 1e-16f);
    float acc = 0.f;
    for (int p = start; p < end; ++p){
        int idx = p - start;
        int s; float ex;
        if (idx < CAP){
            s = isrc[idx];
            ex = exs[idx * 4 + head];
        } else {
            s = csr_src[p];
            uint2 v = alpha[p];
            unsigned short u = (head < 2) ? (unsigned short)(head == 0 ? (v.x & 0xffff) : (v.x >> 16))
                                          : (unsigned short)(head == 2 ? (v.y & 0xffff) : (v.y >> 16));
            ex = bf2f(u);
        }
        acc += ex * bf2f(hh[(size_t)s * HID + t]);
    }
    float y = h[(size_t)n * HID + t] + acc * invd + gat_bias[t];

    float mean = blk_sum128(y, red) * (1.0f / HID);
    float d2 = y - mean;
    float var = blk_sum128(d2 * d2, red) * (1.0f / HID);
    h[(size_t)n * HID + t] = d2 * rsqrtf(var + 1e-5f) * norm_g[t] + norm_b[t];
}

// ---------------- pooling ----------------
__global__ void bounds_kernel(const int* __restrict__ batch, int* __restrict__ bstart){
    int b = threadIdx.x;
    if (b > NB) return;
    int lo = 0, hi = N_NODES;
    while (lo < hi){
        int mid = (lo + hi) >> 1;
        if (batch[mid] < b) lo = mid + 1; else hi = mid;
    }
    bstart[b] = lo;
}

__global__ void pool_kernel(const float* __restrict__ h, const int* __restrict__ bstart,
                            float* __restrict__ psum, float* __restrict__ pmax){
    int b = blockIdx.x, part = blockIdx.y, t = threadIdx.x;
    int s = bstart[b], e = bstart[b + 1];
    int len = e - s;
    int chunk = (len + PARTS - 1) / PARTS;
    int cs = s + part * chunk;
    int ce = min(cs + chunk, e);
    float sum = 0.f, mx = -FLT_MAX;
    for (int n = cs; n < ce; ++n){
        float v = h[(size_t)n * HID + t];
        sum += v; mx = fmaxf(mx, v);
    }
    int slot = (b * PARTS + part) * HID + t;
    psum[slot] = sum;
    pmax[slot] = mx;
}

// ---------------- readout MLP + sigmoid ----------------
__global__ void mlp_kernel(const float* __restrict__ psum, const float* __restrict__ pmax,
                           const int* __restrict__ bstart,
                           const float* __restrict__ fw1, const float* __restrict__ fb1,
                           const float* __restrict__ fw2, const float* __restrict__ fb2,
                           const float* __restrict__ cw1, const float* __restrict__ cb1,
                           const float* __restrict__ cw2, const float* __restrict__ cb2,
                           float* __restrict__ out)
{
    __shared__ float g[256];
    __shared__ float y1[128];
    __shared__ float y2[64];
    __shared__ float y3[64];
    __shared__ float red[2];
    int b = blockIdx.x, t = threadIdx.x;
    float sum = 0.f, mx = -FLT_MAX;
    for (int p = 0; p < PARTS; p++){
        int slot = (b * PARTS + p) * HID + t;
        sum += psum[slot];
        mx = fmaxf(mx, pmax[slot]);
    }
    int cnt = bstart[b + 1] - bstart[b];
    float mean = sum / (float)max(cnt, 1);
    if (cnt <= 0) mx = 0.f;
    g[t] = mean; g[128 + t] = mx;
    __syncthreads();
    float a1 = fb1[t];
    for (int k = 0; k < 256; k++) a1 += g[k] * fw1[k * 128 + t];
    y1[t] = gelu_f(a1);
    __syncthreads();
    if (t < 64){
        float a2 = fb2[t];
        for (int k = 0; k < 128; k++) a2 += y1[k] * fw2[k * 64 + t];
        y2[t] = gelu_f(a2);
    }
    __syncthreads();
    if (t < 64){
        float a3 = cb1[t];
        for (int k = 0; k < 64; k++) a3 += y2[k] * cw1[k * 64 + t];
        y3[t] = gelu_f(a3);
    }
    __syncthreads();
    float v = (t < 64) ? y3[t] * cw2[t] : 0.f;
    float s = blk_sum128(v, red);
    if (t == 0){
        float logit = s + cb2[0];
        out[b] = 1.0f / (1.0f + expf(-logit));
    }
}

extern "C" void kernel_launch(void* const* d_in, const int* in_sizes, int n_in,
                              void* d_out, int out_size, void* d_ws, size_t ws_size,
                              hipStream_t stream)
{
    const float* x         = (const float*)d_in[0];
    const float* edge_attr = (const float*)d_in[1];
    const int*   edge_idx  = (const int*)  d_in[2];
    const int*   batch     = (const int*)  d_in[3];
    const float* enc_w     = (const float*)d_in[4];
    const float* enc_b     = (const float*)d_in[5];
    const float* enc_g     = (const float*)d_in[6];
    const float* enc_beta  = (const float*)d_in[7];
    const float* ee_w      = (const float*)d_in[8];
    const float* ee_b      = (const float*)d_in[9];
    const float* gat_lin_w = (const float*)d_in[10];
    const float* gat_edge_w= (const float*)d_in[11];
    const float* att_src   = (const float*)d_in[12];
    const float* att_dst   = (const float*)d_in[13];
    const float* att_edge  = (const float*)d_in[14];
    const float* gat_bias  = (const float*)d_in[15];
    const float* norm_g    = (const float*)d_in[16];
    const float* norm_b    = (const float*)d_in[17];
    const float* fw1       = (const float*)d_in[18];
    const float* fb1       = (const float*)d_in[19];
    const float* fw2       = (const float*)d_in[20];
    const float* fb2       = (const float*)d_in[21];
    const float* cw1       = (const float*)d_in[22];
    const float* cb1       = (const float*)d_in[23];
    const float* cw2       = (const float*)d_in[24];
    const float* cb2       = (const float*)d_in[25];
    float* out = (float*)d_out;

    char* wsp = (char*)d_ws;
    size_t off = 0;
    auto alloc = [&](size_t bytes) -> void* {
        void* p = wsp + off;
        off += (bytes + 255) & ~(size_t)255;
        return p;
    };
    float*          h        = (float*)alloc((size_t)N_NODES * HID * 4);
    unsigned short* hh       = (unsigned short*)alloc((size_t)N_NODES * HID * 2);
    float*          a_s      = (float*)alloc((size_t)N_NODES * 4 * 4);
    float*          a_d      = (float*)alloc((size_t)N_NODES * 4 * 4);
    uint2*          al0      = (uint2*)alloc((size_t)TOT * 8);
    uint2*          al1      = (uint2*)alloc((size_t)TOT * 8);
    uint2*          al2      = (uint2*)alloc((size_t)TOT * 8);
    int*            csr_src  = (int*)  alloc((size_t)TOT * 4);
    int*            epos     = (int*)  alloc((size_t)N_EDGES * 4);
    int*            self_pos = (int*)  alloc((size_t)N_NODES * 4);
    int*            row_ptr  = (int*)  alloc((size_t)(N_NODES + 1) * 4);
    int*            cursor   = (int*)  alloc((size_t)N_NODES * 4);
    int*            row_count= (int*)  alloc((size_t)N_NODES * 4);
    float*          We3      = (float*)alloc(3 * 64 * 4 * 4);
    int*            bstart   = (int*)  alloc((NB + 1) * 4);
    float*          psum     = (float*)alloc((size_t)NB * PARTS * HID * 4);
    float*          pmax     = (float*)alloc((size_t)NB * PARTS * HID * 4);

    // encoder
    hipLaunchKernelGGL(enc_kernel, dim3(N_NODES), dim3(128), 0, stream,
                       x, enc_w, enc_b, enc_g, enc_beta, h);

    // CSR build
    hipMemsetAsync(row_count, 0, (size_t)N_NODES * 4, stream);
    hipLaunchKernelGGL(count_kernel, dim3((N_EDGES + 255) / 256), dim3(256), 0, stream,
                       edge_idx, row_count);
    hipLaunchKernelGGL(scan_kernel, dim3(1), dim3(1024), 0, stream, row_count, row_ptr);
    hipMemcpyAsync(cursor, row_ptr, (size_t)N_NODES * 4, hipMemcpyDeviceToDevice, stream);
    hipLaunchKernelGGL(scatter_kernel, dim3((TOT + 255) / 256), dim3(256), 0, stream,
                       edge_idx, cursor, csr_src, epos, self_pos);

    // all-layer edge attention terms (one gelu pass total)
    hipLaunchKernelGGL(we3_kernel, dim3(1), dim3(256), 0, stream, gat_edge_w, att_edge, We3);
    hipLaunchKernelGGL(ae_all_kernel, dim3((N_EDGES + 255) / 256), dim3(256), 0, stream,
                       (const float4*)edge_attr, ee_w, ee_b, We3, epos, al0, al1, al2);
    hipLaunchKernelGGL(selfae_kernel, dim3(N_NODES), dim3(64), 0, stream,
                       row_ptr, self_pos, al0, al1, al2);

    // GAT layers
    uint2* als[3] = {al0, al1, al2};
    for (int l = 0; l < 3; l++){
        hipLaunchKernelGGL(gemm_hh_kernel, dim3(N_NODES / GROWS), dim3(128), 0, stream,
                           h, gat_lin_w + (size_t)l * HID * HID,
                           att_src + (size_t)l * HID, att_dst + (size_t)l * HID,
                           hh, a_s, a_d);
        hipLaunchKernelGGL(agg_kernel, dim3(N_NODES), dim3(128), 0, stream,
                           (const float4*)a_s, (const float4*)a_d, row_ptr, csr_src,
                           als[l], hh, h,
                           gat_bias + (size_t)l * HID, norm_g + (size_t)l * HID,
                           norm_b + (size_t)l * HID);
    }

    // pooling + MLP
    hipLaunchKernelGGL(bounds_kernel, dim3(1), dim3(128), 0, stream, batch, bstart);
    hipLaunchKernelGGL(pool_kernel, dim3(NB, PARTS), dim3(128), 0, stream, h, bstart, psum, pmax);
    hipLaunchKernelGGL(mlp_kernel, dim3(NB), dim3(128), 0, stream,
                       psum, pmax, bstart, fw1, fb1, fw2, fb2, cw1, cb1, cw2, cb2, out);
}

// Round 3
// 868.243 us; speedup vs baseline: 1.7144x; 1.4461x over previous
//
#include <hip/hip_runtime.h>
#include <float.h>
#include <math.h>

#define N_NODES 50000
#define N_EDGES 1600000
#define NB      64
#define HID     128
#define TOT     (N_EDGES + N_NODES)
#define PARTS   16
#define CAP     256   // max degree cached in LDS; spill path handles more
#define SCAN_NB 196   // ceil(50000/256)

__device__ __forceinline__ float gelu_f(float x){
    return 0.5f * x * (1.0f + erff(x * 0.70710678118654752440f));
}

__device__ __forceinline__ float bf2f(unsigned short u){
    union { unsigned int i; float f; } c; c.i = ((unsigned int)u) << 16; return c.f;
}
__device__ __forceinline__ unsigned short f2bf(float x){
    union { float f; unsigned int i; } c; c.f = x;
    unsigned int r = c.i + 0x7fffu + ((c.i >> 16) & 1u);
    return (unsigned short)(r >> 16);
}
__device__ __forceinline__ uint2 pack4(float a, float b, float cc, float d){
    uint2 r;
    r.x = (unsigned int)f2bf(a) | ((unsigned int)f2bf(b) << 16);
    r.y = (unsigned int)f2bf(cc) | ((unsigned int)f2bf(d) << 16);
    return r;
}
__device__ __forceinline__ float4 unpack4(uint2 v){
    return make_float4(bf2f(v.x & 0xffff), bf2f(v.x >> 16),
                       bf2f(v.y & 0xffff), bf2f(v.y >> 16));
}

// block of 128 threads (2 waves) sum-reduce; red must be float[>=2] shared
__device__ __forceinline__ float blk_sum128(float v, float* red){
    #pragma unroll
    for (int m = 32; m > 0; m >>= 1) v += __shfl_xor(v, m, 64);
    __syncthreads();
    if ((threadIdx.x & 63) == 0) red[threadIdx.x >> 6] = v;
    __syncthreads();
    float r = red[0] + red[1];
    __syncthreads();
    return r;
}

// inclusive scan across 256 threads; wsum must be int[4] shared
__device__ __forceinline__ int blk_scan256(int v, int* wsum){
    int t = threadIdx.x, lane = t & 63, w = t >> 6;
    int x = v;
    #pragma unroll
    for (int off = 1; off < 64; off <<= 1){
        int y = __shfl_up(x, off, 64);
        if (lane >= off) x += y;
    }
    if (lane == 63) wsum[w] = x;
    __syncthreads();
    if (t == 0){
        int s = 0;
        #pragma unroll
        for (int i = 0; i < 4; i++){ int tmp = wsum[i]; wsum[i] = s; s += tmp; }
    }
    __syncthreads();
    return x + wsum[w];
}

// ---------------- encoder: h = gelu(LN(x@enc_w+enc_b)) ----------------
__global__ void enc_kernel(const float* __restrict__ x, const float* __restrict__ enc_w,
                           const float* __restrict__ enc_b, const float* __restrict__ enc_g,
                           const float* __restrict__ enc_beta, float* __restrict__ h)
{
    __shared__ float xs[12];
    __shared__ float red[2];
    int n = blockIdx.x, t = threadIdx.x;
    if (t < 12) xs[t] = x[n * 12 + t];
    __syncthreads();
    float acc = enc_b[t];
    #pragma unroll
    for (int k = 0; k < 12; k++) acc += xs[k] * enc_w[k * HID + t];
    float mean = blk_sum128(acc, red) * (1.0f / HID);
    float d = acc - mean;
    float var = blk_sum128(d * d, red) * (1.0f / HID);
    float y = d * rsqrtf(var + 1e-5f) * enc_g[t] + enc_beta[t];
    h[(size_t)n * HID + t] = gelu_f(y);
}

// ---------------- CSR build ----------------
__global__ void count_kernel(const int* __restrict__ ei, int* __restrict__ row_count){
    int i = blockIdx.x * 256 + threadIdx.x;
    if (i < N_EDGES) atomicAdd(&row_count[ei[N_EDGES + i]], 1);
}

// per-block totals of (count+1)
__global__ void scan1_kernel(const int* __restrict__ row_count, int* __restrict__ bsum){
    __shared__ int ws[4];
    int i = blockIdx.x * 256 + threadIdx.x;
    int v = (i < N_NODES) ? (row_count[i] + 1) : 0;
    int x = v;
    #pragma unroll
    for (int m = 32; m > 0; m >>= 1) x += __shfl_xor(x, m, 64);
    if ((threadIdx.x & 63) == 0) ws[threadIdx.x >> 6] = x;
    __syncthreads();
    if (threadIdx.x == 0) bsum[blockIdx.x] = ws[0] + ws[1] + ws[2] + ws[3];
}

// exclusive scan of the 196 block sums (single small block)
__global__ void scan2_kernel(int* __restrict__ bsum){
    __shared__ int ws[4];
    int t = threadIdx.x;
    int v = (t < SCAN_NB) ? bsum[t] : 0;
    int incl = blk_scan256(v, ws);
    if (t < SCAN_NB) bsum[t] = incl - v;   // exclusive
}

// per-block rescan + offset -> row_ptr and cursor
__global__ void scan3_kernel(const int* __restrict__ row_count, const int* __restrict__ bsum,
                             int* __restrict__ row_ptr, int* __restrict__ cursor){
    __shared__ int ws[4];
    int i = blockIdx.x * 256 + threadIdx.x;
    int v = (i < N_NODES) ? (row_count[i] + 1) : 0;
    int incl = blk_scan256(v, ws) + bsum[blockIdx.x];
    if (i < N_NODES){
        row_ptr[i + 1] = incl;
        cursor[i] = incl - v;
    }
    if (i == 0) row_ptr[0] = 0;
}

__global__ void scatter_kernel(const int* __restrict__ ei, int* __restrict__ cursor,
                               int* __restrict__ csr_src, int* __restrict__ epos,
                               int* __restrict__ self_pos){
    int i = blockIdx.x * 256 + threadIdx.x;
    if (i >= TOT) return;
    int s, d;
    if (i < N_EDGES){ s = ei[i]; d = ei[N_EDGES + i]; }
    else { s = d = i - N_EDGES; }
    int pos = atomicAdd(&cursor[d], 1);
    csr_src[pos] = s;
    if (i < N_EDGES) epos[i] = pos; else self_pos[d] = pos;
}

// ---------------- We3[l][k][h] = sum_c gat_edge_w[l][k][h*32+c]*att_edge[l][h*32+c] ----------------
__global__ void we3_kernel(const float* __restrict__ gat_edge_w, const float* __restrict__ att_edge,
                           float* __restrict__ We3)
{
    int t = threadIdx.x;          // 256 threads
    int k = t >> 2, hd = t & 3;
    for (int l = 0; l < 3; l++){
        float s = 0.f;
        #pragma unroll
        for (int c = 0; c < 32; c++)
            s += gat_edge_w[(size_t)l * 64 * HID + k * HID + hd * 32 + c]
               * att_edge[l * HID + hd * 32 + c];
        We3[(l * 64 + k) * 4 + hd] = s;
    }
}

// ---------------- per-edge a_e for ALL 3 layers, scattered to CSR position order ----------------
__global__ void ae_all_kernel(const float4* __restrict__ edge_attr, const float* __restrict__ ee_w,
                              const float* __restrict__ ee_b, const float* __restrict__ We3,
                              const int* __restrict__ epos,
                              uint2* __restrict__ al0, uint2* __restrict__ al1, uint2* __restrict__ al2)
{
    int e = blockIdx.x * 256 + threadIdx.x;
    if (e >= N_EDGES) return;
    float4 ea = edge_attr[e];
    float acc[12];
    #pragma unroll
    for (int i = 0; i < 12; i++) acc[i] = 0.f;
    #pragma unroll 4
    for (int k = 0; k < 64; k++){
        float v = gelu_f(ea.x * ee_w[k] + ea.y * ee_w[64 + k] + ea.z * ee_w[128 + k]
                         + ea.w * ee_w[192 + k] + ee_b[k]);
        #pragma unroll
        for (int l = 0; l < 3; l++){
            float4 wv = ((const float4*)We3)[l * 64 + k];
            acc[l*4+0] += v * wv.x; acc[l*4+1] += v * wv.y;
            acc[l*4+2] += v * wv.z; acc[l*4+3] += v * wv.w;
        }
    }
    int p = epos[e];
    al0[p] = pack4(acc[0], acc[1], acc[2],  acc[3]);
    al1[p] = pack4(acc[4], acc[5], acc[6],  acc[7]);
    al2[p] = pack4(acc[8], acc[9], acc[10], acc[11]);
}

// ---------------- self-loop a_e = mean over incoming real edges (linearity of the dot) ----------------
__global__ void selfae_kernel(const int* __restrict__ row_ptr, const int* __restrict__ self_pos,
                              uint2* __restrict__ al0, uint2* __restrict__ al1, uint2* __restrict__ al2)
{
    __shared__ float s[48];
    int n = blockIdx.x, t = threadIdx.x;   // 64 threads
    int start = row_ptr[n], end = row_ptr[n + 1], sp = self_pos[n];
    int deg = end - start - 1;
    if (t < 48){
        int g = t / 12, c = t % 12, l = c >> 2, hd = c & 3;
        const unsigned short* buf = (const unsigned short*)(l == 0 ? al0 : l == 1 ? al1 : al2);
        float sum = 0.f;
        for (int p = start + g; p < end; p += 4){
            if (p == sp) continue;
            sum += bf2f(buf[(size_t)p * 4 + hd]);
        }
        s[t] = sum;
    }
    __syncthreads();
    if (t < 12){
        int l = t >> 2, hd = t & 3;
        float m = (s[t] + s[t + 12] + s[t + 24] + s[t + 36]) / (float)max(deg, 1);
        unsigned short* buf = (unsigned short*)(l == 0 ? al0 : l == 1 ? al1 : al2);
        buf[(size_t)sp * 4 + hd] = f2bf(m);
    }
}

// ---------------- per-layer GEMM hh = h @ W (bf16 out), fused a_s/a_d ----------------
#define GROWS 8
__global__ void gemm_hh_kernel(const float* __restrict__ h, const float* __restrict__ W,
                               const float* __restrict__ att_s, const float* __restrict__ att_d,
                               unsigned short* __restrict__ hh, float* __restrict__ a_s,
                               float* __restrict__ a_d)
{
    __shared__ float lh[GROWS * HID];
    int t = threadIdx.x;
    int n0 = blockIdx.x * GROWS;
    #pragma unroll
    for (int r = 0; r < GROWS; r++) lh[r * HID + t] = h[(size_t)(n0 + r) * HID + t];
    __syncthreads();
    float acc[GROWS];
    #pragma unroll
    for (int r = 0; r < GROWS; r++) acc[r] = 0.f;
    for (int k = 0; k < HID; k++){
        float w = W[k * HID + t];
        #pragma unroll
        for (int r = 0; r < GROWS; r++) acc[r] += lh[r * HID + k] * w;
    }
    float as_w = att_s[t], ad_w = att_d[t];
    int head = t >> 5;
    #pragma unroll
    for (int r = 0; r < GROWS; r++){
        hh[(size_t)(n0 + r) * HID + t] = f2bf(acc[r]);
        float vs = acc[r] * as_w, vd = acc[r] * ad_w;
        #pragma unroll
        for (int m = 16; m > 0; m >>= 1){
            vs += __shfl_xor(vs, m, 32);
            vd += __shfl_xor(vd, m, 32);
        }
        if ((t & 31) == 0){
            a_s[(n0 + r) * 4 + head] = vs;
            a_d[(n0 + r) * 4 + head] = vd;
        }
    }
}

// ---------------- fused: leaky+exp+segsum+aggregate+residual+LN ----------------
__global__ void agg_kernel(const float4* __restrict__ a_s, const float4* __restrict__ a_d,
                           const int* __restrict__ row_ptr, const int* __restrict__ csr_src,
                           uint2* __restrict__ alpha, const uint2* __restrict__ hhv,
                           float* __restrict__ h, const float* __restrict__ gat_bias,
                           const float* __restrict__ norm_g, const float* __restrict__ norm_b)
{
    __shared__ float exs[CAP * 4];
    __shared__ int   isrc[CAP];
    __shared__ float accbuf[4 * HID];
    __shared__ float red[8];
    int n = blockIdx.x, t = threadIdx.x;
    int start = row_ptr[n], end = row_ptr[n + 1];
    float4 ad = a_d[n];

    // phase A: alpha = leaky(a_s[src]+a_d[n]+a_e); ex = exp(alpha); segment sum
    float4 sm = make_float4(0.f, 0.f, 0.f, 0.f);
    for (int p = start + t; p < end; p += 128){
        int idx = p - start;
        int s = csr_src[p];
        float4 as = a_s[s];
        float4 ae = unpack4(alpha[p]);
        float4 al;
        al.x = as.x + ad.x + ae.x; al.x = al.x > 0.f ? al.x : 0.2f * al.x;
        al.y = as.y + ad.y + ae.y; al.y = al.y > 0.f ? al.y : 0.2f * al.y;
        al.z = as.z + ad.z + ae.z; al.z = al.z > 0.f ? al.z : 0.2f * al.z;
        al.w = as.w + ad.w + ae.w; al.w = al.w > 0.f ? al.w : 0.2f * al.w;
        float4 e;
        e.x = __expf(al.x); e.y = __expf(al.y); e.z = __expf(al.z); e.w = __expf(al.w);
        sm.x += e.x; sm.y += e.y; sm.z += e.z; sm.w += e.w;
        if (idx < CAP){
            exs[idx*4+0] = e.x; exs[idx*4+1] = e.y; exs[idx*4+2] = e.z; exs[idx*4+3] = e.w;
            isrc[idx] = s;
        } else {
            alpha[p] = pack4(e.x, e.y, e.z, e.w);   // spill (rare)
        }
    }
    #pragma unroll
    for (int m = 32; m > 0; m >>= 1){
        sm.x += __shfl_xor(sm.x, m, 64); sm.y += __shfl_xor(sm.y, m, 64);
        sm.z += __shfl_xor(sm.z, m, 64); sm.w += __shfl_xor(sm.w, m, 64);
    }
    __syncthreads();
    if ((t & 63) == 0){ int w = t >> 6; red[w*4+0]=sm.x; red[w*4+1]=sm.y; red[w*4+2]=sm.z; red[w*4+3]=sm.w; }
    __syncthreads();
    float4 D;
    D.x = red[0] + red[4]; D.y = red[1] + red[5];
    D.z = red[2] + red[6]; D.w = red[3] + red[7];
    __syncthreads();

    // phase B: edge-parallel gather. 4 groups x 32 lanes; lane ln covers channels 4ln..4ln+3
    int g = t >> 5, ln = t & 31;
    int hd2 = ln >> 3;                       // head of channels 4ln..4ln+3
    float4 acc4 = make_float4(0.f, 0.f, 0.f, 0.f);

    int p = start + g;
    while (p + 4 < end){
        int i0 = p - start, i1 = i0 + 4;
        int s0, s1; float e0, e1;
        if (i0 < CAP){ s0 = isrc[i0]; e0 = exs[i0*4 + hd2]; }
        else { s0 = csr_src[p]; uint2 v = alpha[p];
               unsigned short u = (hd2 & 2) ? ((hd2 & 1) ? (unsigned short)(v.y >> 16) : (unsigned short)(v.y & 0xffff))
                                            : ((hd2 & 1) ? (unsigned short)(v.x >> 16) : (unsigned short)(v.x & 0xffff));
               e0 = bf2f(u); }
        if (i1 < CAP){ s1 = isrc[i1]; e1 = exs[i1*4 + hd2]; }
        else { s1 = csr_src[p+4]; uint2 v = alpha[p+4];
               unsigned short u = (hd2 & 2) ? ((hd2 & 1) ? (unsigned short)(v.y >> 16) : (unsigned short)(v.y & 0xffff))
                                            : ((hd2 & 1) ? (unsigned short)(v.x >> 16) : (unsigned short)(v.x & 0xffff));
               e1 = bf2f(u); }
        uint2 hv0 = hhv[(size_t)s0 * 32 + ln];
        uint2 hv1 = hhv[(size_t)s1 * 32 + ln];
        float4 h0 = unpack4(hv0), h1 = unpack4(hv1);
        acc4.x += e0 * h0.x; acc4.y += e0 * h0.y; acc4.z += e0 * h0.z; acc4.w += e0 * h0.w;
        acc4.x += e1 * h1.x; acc4.y += e1 * h1.y; acc4.z += e1 * h1.z; acc4.w += e1 * h1.w;
        p += 8;
    }
    if (p < end){
        int i0 = p - start;
        int s0; float e0;
        if (i0 < CAP){ s0 = isrc[i0]; e0 = exs[i0*4 + hd2]; }
        else { s0 = csr_src[p]; uint2 v = alpha[p];
               unsigned short u = (hd2 & 2) ? ((hd2 & 1) ? (unsigned short)(v.y >> 16) : (unsigned short)(v.y & 0xffff))
                                            : ((hd2 & 1) ? (unsigned short)(v.x >> 16) : (unsigned short)(v.x & 0xffff));
               e0 = bf2f(u); }
        uint2 hv0 = hhv[(size_t)s0 * 32 + ln];
        float4 h0 = unpack4(hv0);
        acc4.x += e0 * h0.x; acc4.y += e0 * h0.y; acc4.z += e0 * h0.z; acc4.w += e0 * h0.w;
    }
    ((float4*)accbuf)[g * 32 + ln] = acc4;
    __syncthreads();
    float accT = accbuf[t] + accbuf[HID + t] + accbuf[2*HID + t] + accbuf[3*HID + t];

    int head = t >> 5;
    float Dh = (head == 0) ? D.x : (head == 1) ? D.y : (head == 2) ? D.z : D.w;
    float invd = 1.0f / (Dh + 1e-16f);
    float y = h[(size_t)n * HID + t] + accT * invd + gat_bias[t];

    float mean = blk_sum128(y, red) * (1.0f / HID);
    float d2 = y - mean;
    float var = blk_sum128(d2 * d2, red) * (1.0f / HID);
    h[(size_t)n * HID + t] = d2 * rsqrtf(var + 1e-5f) * norm_g[t] + norm_b[t];
}

// ---------------- pooling ----------------
__global__ void bounds_kernel(const int* __restrict__ batch, int* __restrict__ bstart){
    int b = threadIdx.x;
    if (b > NB) return;
    int lo = 0, hi = N_NODES;
    while (lo < hi){
        int mid = (lo + hi) >> 1;
        if (batch[mid] < b) lo = mid + 1; else hi = mid;
    }
    bstart[b] = lo;
}

__global__ void pool_kernel(const float* __restrict__ h, const int* __restrict__ bstart,
                            float* __restrict__ psum, float* __restrict__ pmax){
    int b = blockIdx.x, part = blockIdx.y, t = threadIdx.x;
    int s = bstart[b], e = bstart[b + 1];
    int len = e - s;
    int chunk = (len + PARTS - 1) / PARTS;
    int cs = s + part * chunk;
    int ce = min(cs + chunk, e);
    float sum = 0.f, mx = -FLT_MAX;
    for (int n = cs; n < ce; ++n){
        float v = h[(size_t)n * HID + t];
        sum += v; mx = fmaxf(mx, v);
    }
    int slot = (b * PARTS + part) * HID + t;
    psum[slot] = sum;
    pmax[slot] = mx;
}

// ---------------- readout MLP + sigmoid ----------------
__global__ void mlp_kernel(const float* __restrict__ psum, const float* __restrict__ pmax,
                           const int* __restrict__ bstart,
                           const float* __restrict__ fw1, const float* __restrict__ fb1,
                           const float* __restrict__ fw2, const float* __restrict__ fb2,
                           const float* __restrict__ cw1, const float* __restrict__ cb1,
                           const float* __restrict__ cw2, const float* __restrict__ cb2,
                           float* __restrict__ out)
{
    __shared__ float g[256];
    __shared__ float y1[128];
    __shared__ float y2[64];
    __shared__ float y3[64];
    __shared__ float red[2];
    int b = blockIdx.x, t = threadIdx.x;
    float sum = 0.f, mx = -FLT_MAX;
    for (int p = 0; p < PARTS; p++){
        int slot = (b * PARTS + p) * HID + t;
        sum += psum[slot];
        mx = fmaxf(mx, pmax[slot]);
    }
    int cnt = bstart[b + 1] - bstart[b];
    float mean = sum / (float)max(cnt, 1);
    if (cnt <= 0) mx = 0.f;
    g[t] = mean; g[128 + t] = mx;
    __syncthreads();
    float a1 = fb1[t];
    for (int k = 0; k < 256; k++) a1 += g[k] * fw1[k * 128 + t];
    y1[t] = gelu_f(a1);
    __syncthreads();
    if (t < 64){
        float a2 = fb2[t];
        for (int k = 0; k < 128; k++) a2 += y1[k] * fw2[k * 64 + t];
        y2[t] = gelu_f(a2);
    }
    __syncthreads();
    if (t < 64){
        float a3 = cb1[t];
        for (int k = 0; k < 64; k++) a3 += y2[k] * cw1[k * 64 + t];
        y3[t] = gelu_f(a3);
    }
    __syncthreads();
    float v = (t < 64) ? y3[t] * cw2[t] : 0.f;
    float s = blk_sum128(v, red);
    if (t == 0){
        float logit = s + cb2[0];
        out[b] = 1.0f / (1.0f + expf(-logit));
    }
}

extern "C" void kernel_launch(void* const* d_in, const int* in_sizes, int n_in,
                              void* d_out, int out_size, void* d_ws, size_t ws_size,
                              hipStream_t stream)
{
    const float* x         = (const float*)d_in[0];
    const float* edge_attr = (const float*)d_in[1];
    const int*   edge_idx  = (const int*)  d_in[2];
    const int*   batch     = (const int*)  d_in[3];
    const float* enc_w     = (const float*)d_in[4];
    const float* enc_b     = (const float*)d_in[5];
    const float* enc_g     = (const float*)d_in[6];
    const float* enc_beta  = (const float*)d_in[7];
    const float* ee_w      = (const float*)d_in[8];
    const float* ee_b      = (const float*)d_in[9];
    const float* gat_lin_w = (const float*)d_in[10];
    const float* gat_edge_w= (const float*)d_in[11];
    const float* att_src   = (const float*)d_in[12];
    const float* att_dst   = (const float*)d_in[13];
    const float* att_edge  = (const float*)d_in[14];
    const float* gat_bias  = (const float*)d_in[15];
    const float* norm_g    = (const float*)d_in[16];
    const float* norm_b    = (const float*)d_in[17];
    const float* fw1       = (const float*)d_in[18];
    const float* fb1       = (const float*)d_in[19];
    const float* fw2       = (const float*)d_in[20];
    const float* fb2       = (const float*)d_in[21];
    const float* cw1       = (const float*)d_in[22];
    const float* cb1       = (const float*)d_in[23];
    const float* cw2       = (const float*)d_in[24];
    const float* cb2       = (const float*)d_in[25];
    float* out = (float*)d_out;

    char* wsp = (char*)d_ws;
    size_t off = 0;
    auto alloc = [&](size_t bytes) -> void* {
        void* p = wsp + off;
        off += (bytes + 255) & ~(size_t)255;
        return p;
    };
    float*          h        = (float*)alloc((size_t)N_NODES * HID * 4);
    unsigned short* hh       = (unsigned short*)alloc((size_t)N_NODES * HID * 2);
    float*          a_s      = (float*)alloc((size_t)N_NODES * 4 * 4);
    float*          a_d      = (float*)alloc((size_t)N_NODES * 4 * 4);
    uint2*          al0      = (uint2*)alloc((size_t)TOT * 8);
    uint2*          al1      = (uint2*)alloc((size_t)TOT * 8);
    uint2*          al2      = (uint2*)alloc((size_t)TOT * 8);
    int*            csr_src  = (int*)  alloc((size_t)TOT * 4);
    int*            epos     = (int*)  alloc((size_t)N_EDGES * 4);
    int*            self_pos = (int*)  alloc((size_t)N_NODES * 4);
    int*            row_ptr  = (int*)  alloc((size_t)(N_NODES + 1) * 4);
    int*            cursor   = (int*)  alloc((size_t)N_NODES * 4);
    int*            row_count= (int*)  alloc((size_t)N_NODES * 4);
    int*            bsum     = (int*)  alloc((size_t)SCAN_NB * 4);
    float*          We3      = (float*)alloc(3 * 64 * 4 * 4);
    int*            bstart   = (int*)  alloc((NB + 1) * 4);
    float*          psum     = (float*)alloc((size_t)NB * PARTS * HID * 4);
    float*          pmax     = (float*)alloc((size_t)NB * PARTS * HID * 4);

    // encoder
    hipLaunchKernelGGL(enc_kernel, dim3(N_NODES), dim3(128), 0, stream,
                       x, enc_w, enc_b, enc_g, enc_beta, h);

    // CSR build (multi-block scan)
    hipMemsetAsync(row_count, 0, (size_t)N_NODES * 4, stream);
    hipLaunchKernelGGL(count_kernel, dim3((N_EDGES + 255) / 256), dim3(256), 0, stream,
                       edge_idx, row_count);
    hipLaunchKernelGGL(scan1_kernel, dim3(SCAN_NB), dim3(256), 0, stream, row_count, bsum);
    hipLaunchKernelGGL(scan2_kernel, dim3(1), dim3(256), 0, stream, bsum);
    hipLaunchKernelGGL(scan3_kernel, dim3(SCAN_NB), dim3(256), 0, stream,
                       row_count, bsum, row_ptr, cursor);
    hipLaunchKernelGGL(scatter_kernel, dim3((TOT + 255) / 256), dim3(256), 0, stream,
                       edge_idx, cursor, csr_src, epos, self_pos);

    // all-layer edge attention terms (one gelu pass total)
    hipLaunchKernelGGL(we3_kernel, dim3(1), dim3(256), 0, stream, gat_edge_w, att_edge, We3);
    hipLaunchKernelGGL(ae_all_kernel, dim3((N_EDGES + 255) / 256), dim3(256), 0, stream,
                       (const float4*)edge_attr, ee_w, ee_b, We3, epos, al0, al1, al2);
    hipLaunchKernelGGL(selfae_kernel, dim3(N_NODES), dim3(64), 0, stream,
                       row_ptr, self_pos, al0, al1, al2);

    // GAT layers
    uint2* als[3] = {al0, al1, al2};
    for (int l = 0; l < 3; l++){
        hipLaunchKernelGGL(gemm_hh_kernel, dim3(N_NODES / GROWS), dim3(128), 0, stream,
                           h, gat_lin_w + (size_t)l * HID * HID,
                           att_src + (size_t)l * HID, att_dst + (size_t)l * HID,
                           hh, a_s, a_d);
        hipLaunchKernelGGL(agg_kernel, dim3(N_NODES), dim3(128), 0, stream,
                           (const float4*)a_s, (const float4*)a_d, row_ptr, csr_src,
                           als[l], (const uint2*)hh, h,
                           gat_bias + (size_t)l * HID, norm_g + (size_t)l * HID,
                           norm_b + (size_t)l * HID);
    }

    // pooling + MLP
    hipLaunchKernelGGL(bounds_kernel, dim3(1), dim3(128), 0, stream, batch, bstart);
    hipLaunchKernelGGL(pool_kernel, dim3(NB, PARTS), dim3(128), 0, stream, h, bstart, psum, pmax);
    hipLaunchKernelGGL(mlp_kernel, dim3(NB), dim3(128), 0, stream,
                       psum, pmax, bstart, fw1, fb1, fw2, fb2, cw1, cb1, cw2, cb2, out);
}